// Round 1
// baseline (2054.819 us; speedup 1.0000x reference)
//
#include <hip/hip_runtime.h>

constexpr int kH    = 1024;
constexpr int kNT   = 16384;   // B*S tokens
constexpr int kE    = 4;
constexpr int kC    = 1024;
constexpr int kR    = 4;
constexpr int kKeep = 512;
constexpr float kLoraScale = 0.25f;  // ALPHA / R

// ws layout (float offsets)
constexpr size_t WS_RW     = 0;        // kNT*kE          = 65536
constexpr size_t WS_L      = 65536;    // kNT*kE*kR       = 262144
constexpr size_t WS_XSUM   = 327680;   // kH              = 1024
constexpr size_t WS_SHADOW = 328704;   // 64*8            = 512
constexpr size_t WS_BIAS   = 329216;   // kE*kH           = 4096
constexpr size_t WS_NEWV0  = 333312;   // kE*kH           = 4096
// total 337408 floats (~1.35 MB)

// out layout (float offsets)
constexpr size_t OUT_LB = 16777216;            // scalar
constexpr size_t OUT_NK = 16777217;            // then NV, NI contiguous

__device__ __forceinline__ float wred(float v) {
#pragma unroll
  for (int off = 32; off; off >>= 1) v += __shfl_xor(v, off);
  return v;
}

// ---- router: logits, softmax, top-2, dense routing weights, x@Ae, lb stats ----
__global__ __launch_bounds__(256) void router_k(
    const float* __restrict__ x, const float* __restrict__ Wg,
    const float* __restrict__ bg, const float* __restrict__ Ae,
    float* __restrict__ rw, float* __restrict__ Lw, float* __restrict__ shadow) {
  __shared__ float sblk[4][8];
  const int wave = threadIdx.x >> 6, lane = threadIdx.x & 63;
  const int t = blockIdx.x * 4 + wave;
  const float* xt = x + (size_t)t * kH;
  float p[kE] = {};
  float la[kE][kR] = {};
  for (int i = lane; i < kH; i += 64) {
    const float xv = xt[i];
    const float4 wg = *(const float4*)(Wg + (size_t)i * kE);
    p[0] += xv * wg.x; p[1] += xv * wg.y; p[2] += xv * wg.z; p[3] += xv * wg.w;
#pragma unroll
    for (int e = 0; e < kE; ++e) {
      const float4 ae = *(const float4*)(Ae + ((size_t)e * kH + i) * kR);
      la[e][0] += xv * ae.x; la[e][1] += xv * ae.y;
      la[e][2] += xv * ae.z; la[e][3] += xv * ae.w;
    }
  }
#pragma unroll
  for (int e = 0; e < kE; ++e) {
    p[e] = wred(p[e]);
#pragma unroll
    for (int r = 0; r < kR; ++r) la[e][r] = wred(la[e][r]);
  }
  if (lane == 0) {
    float lg[kE];
#pragma unroll
    for (int e = 0; e < kE; ++e) lg[e] = p[e] + bg[e];
    const float mx = fmaxf(fmaxf(lg[0], lg[1]), fmaxf(lg[2], lg[3]));
    float ex[kE], se = 0.f;
#pragma unroll
    for (int e = 0; e < kE; ++e) { ex[e] = __expf(lg[e] - mx); se += ex[e]; }
    float pr[kE];
#pragma unroll
    for (int e = 0; e < kE; ++e) pr[e] = ex[e] / se;
    int e1 = 0;
#pragma unroll
    for (int e = 1; e < kE; ++e) if (pr[e] > pr[e1]) e1 = e;
    int e2 = (e1 == 0) ? 1 : 0;
#pragma unroll
    for (int e = 0; e < kE; ++e) if (e != e1 && pr[e] > pr[e2]) e2 = e;
    const float s2 = pr[e1] + pr[e2];
    float rwv[kE] = {0.f, 0.f, 0.f, 0.f};
    rwv[e1] = pr[e1] / s2; rwv[e2] = pr[e2] / s2;
    *(float4*)(rw + (size_t)t * kE) = make_float4(rwv[0], rwv[1], rwv[2], rwv[3]);
#pragma unroll
    for (int e = 0; e < kE; ++e)
      *(float4*)(Lw + ((size_t)t * kE + e) * kR) =
          make_float4(la[e][0], la[e][1], la[e][2], la[e][3]);
#pragma unroll
    for (int e = 0; e < kE; ++e) {
      sblk[wave][e] = pr[e];
      sblk[wave][4 + e] = ((e == e1) ? 1.f : 0.f) + ((e == e2) ? 1.f : 0.f);
    }
  }
  __syncthreads();
  if (threadIdx.x < 8) {
    const float v = sblk[0][threadIdx.x] + sblk[1][threadIdx.x] +
                    sblk[2][threadIdx.x] + sblk[3][threadIdx.x];
    atomicAdd(&shadow[(blockIdx.x & 63) * 8 + threadIdx.x], v);
  }
}

// ---- column sums of x -> xsum (for x.mean((0,1))) ----
__global__ __launch_bounds__(256) void colsum_k(const float* __restrict__ x,
                                                float* __restrict__ xsum) {
  const int cg = blockIdx.x & 3, rg = blockIdx.x >> 2;
  const int col = cg * 256 + threadIdx.x;
  const float* p = x + (size_t)rg * 256 * kH + col;
  float s = 0.f;
  for (int r = 0; r < 256; ++r) s += p[(size_t)r * kH];
  atomicAdd(&xsum[col], s);
}

// ---- per-expert: top-512 select, vbar, value-LoRA mean, bias, new_values row0 ----
__global__ __launch_bounds__(256) void expert_k(
    const float* __restrict__ ci, const float* __restrict__ cv,
    const float* __restrict__ Av, const float* __restrict__ Bv,
    const float* __restrict__ be, const float* __restrict__ We,
    const float* __restrict__ Ae, const float* __restrict__ Bee,
    const float* __restrict__ xsum, float* __restrict__ bias_ws,
    float* __restrict__ newv0_ws) {
  __shared__ float imp[kC];
  __shared__ unsigned char keep[kC];
  __shared__ float xmean[kH];
  __shared__ float red[256];
  __shared__ float tu[8];
  const int e = blockIdx.x, tid = threadIdx.x;
  for (int c = tid; c < kC; c += 256) imp[c] = ci[(size_t)e * kC + c];
  for (int h = tid; h < kH; h += 256) xmean[h] = xsum[h] * (1.0f / kNT);
  __syncthreads();
  // stable rank (ties -> lower index first, matching jax.lax.top_k)
  for (int c = tid; c < kC; c += 256) {
    const float v = imp[c];
    int rank = 0;
    for (int c2 = 0; c2 < kC; ++c2) {
      const float v2 = imp[c2];
      rank += (v2 > v) || (v2 == v && c2 < c);
    }
    keep[c] = (rank < kKeep) ? 1 : 0;
  }
  __syncthreads();
  // vbar = mean of kept cache_values rows
  float vb[4] = {0.f, 0.f, 0.f, 0.f};
  const float* cve = cv + (size_t)e * kC * kH;
  for (int r = 0; r < kC; ++r) {
    if (keep[r]) {
      const float* row = cve + (size_t)r * kH;
#pragma unroll
      for (int q = 0; q < 4; ++q) vb[q] += row[tid + q * 256];
    }
  }
#pragma unroll
  for (int q = 0; q < 4; ++q) vb[q] *= (1.0f / kKeep);
  // t_r = vbar @ Av ; u_r = xmean @ Ae  (block reductions)
  for (int j = 0; j < 8; ++j) {
    const int r = j & 3;
    float partial = 0.f;
    if (j < 4) {
#pragma unroll
      for (int q = 0; q < 4; ++q) {
        const int h = tid + q * 256;
        partial += vb[q] * Av[((size_t)e * kH + h) * kR + r];
      }
    } else {
#pragma unroll
      for (int q = 0; q < 4; ++q) {
        const int h = tid + q * 256;
        partial += xmean[h] * Ae[((size_t)e * kH + h) * kR + r];
      }
    }
    red[tid] = partial; __syncthreads();
    for (int s2 = 128; s2; s2 >>= 1) {
      if (tid < s2) red[tid] += red[tid + s2];
      __syncthreads();
    }
    if (tid == 0) tu[j] = red[0];
    __syncthreads();
  }
  // mv = vbar + 0.25 * (t @ Bv); bias = be + mv
  float mvq[4];
#pragma unroll
  for (int q = 0; q < 4; ++q) {
    const int h = tid + q * 256;
    float l = 0.f;
#pragma unroll
    for (int r = 0; r < kR; ++r) l += tu[r] * Bv[((size_t)e * kR + r) * kH + h];
    mvq[q] = vb[q] + kLoraScale * l;
    bias_ws[(size_t)e * kH + h] = be[(size_t)e * kH + h] + mvq[q];
  }
  // fx = xmean @ We ; newv0 = fx + 0.25*(u @ Be) + be + mv
  float fx[4] = {0.f, 0.f, 0.f, 0.f};
  const float* Wee = We + (size_t)e * kH * kH;
  for (int i = 0; i < kH; ++i) {
    const float xm = xmean[i];
#pragma unroll
    for (int q = 0; q < 4; ++q) fx[q] += xm * Wee[(size_t)i * kH + tid + q * 256];
  }
#pragma unroll
  for (int q = 0; q < 4; ++q) {
    const int h = tid + q * 256;
    float l = 0.f;
#pragma unroll
    for (int r = 0; r < kR; ++r) l += tu[4 + r] * Bee[((size_t)e * kR + r) * kH + h];
    newv0_ws[(size_t)e * kH + h] =
        fx[q] + kLoraScale * l + be[(size_t)e * kH + h] + mvq[q];
  }
}

// ---- main fused GEMM: out[t][j] = sum_e rw[t][e]*(x@We_e + bias_e + lora_e)[t][j] ----
__global__ __launch_bounds__(256) void moe_gemm_k(
    const float* __restrict__ x, const float* __restrict__ We,
    const float* __restrict__ Bee, const float* __restrict__ rw,
    const float* __restrict__ Lw, const float* __restrict__ bias,
    float* __restrict__ out) {
  constexpr int BM = 64, BN = 64, BK = 16;
  __shared__ __align__(16) float As[BK][BM];           // transposed A tile
  __shared__ __align__(16) float Bs[kE][BK][BN];
  const int tid = threadIdx.x;
  const int t0 = blockIdx.x * BM;
  const int c0 = blockIdx.y * BN;
  const int tx = tid & 15, ty = tid >> 4;
  const int arow = tid >> 2, aq = tid & 3;
  const int brow = tid >> 4, bq = tid & 15;
  float acc[kE][4][4] = {};
  for (int k = 0; k < kH; k += BK) {
    const float4 av = *(const float4*)(x + (size_t)(t0 + arow) * kH + k + aq * 4);
    As[aq * 4 + 0][arow] = av.x; As[aq * 4 + 1][arow] = av.y;
    As[aq * 4 + 2][arow] = av.z; As[aq * 4 + 3][arow] = av.w;
#pragma unroll
    for (int e = 0; e < kE; ++e)
      *(float4*)&Bs[e][brow][bq * 4] =
          *(const float4*)(We + ((size_t)e * kH + k + brow) * kH + c0 + bq * 4);
    __syncthreads();
#pragma unroll
    for (int kk = 0; kk < BK; ++kk) {
      const float4 a4 = *(const float4*)&As[kk][ty * 4];
      const float a[4] = {a4.x, a4.y, a4.z, a4.w};
#pragma unroll
      for (int e = 0; e < kE; ++e) {
        const float4 b4 = *(const float4*)&Bs[e][kk][tx * 4];
        const float b[4] = {b4.x, b4.y, b4.z, b4.w};
#pragma unroll
        for (int m = 0; m < 4; ++m)
#pragma unroll
          for (int n = 0; n < 4; ++n) acc[e][m][n] += a[m] * b[n];
      }
    }
    __syncthreads();
  }
#pragma unroll
  for (int m = 0; m < 4; ++m) {
    const int t = t0 + ty * 4 + m;
    const float4 w4 = *(const float4*)(rw + (size_t)t * kE);
    const float wv[4] = {w4.x, w4.y, w4.z, w4.w};
    float o[4] = {0.f, 0.f, 0.f, 0.f};
#pragma unroll
    for (int e = 0; e < kE; ++e) {
      if (wv[e] != 0.0f) {
        const float4 l4 = *(const float4*)(Lw + ((size_t)t * kE + e) * kR);
        const float lr[4] = {l4.x, l4.y, l4.z, l4.w};
        const float4 bi4 = *(const float4*)(bias + (size_t)e * kH + c0 + tx * 4);
        float lo[4] = {0.f, 0.f, 0.f, 0.f};
#pragma unroll
        for (int r = 0; r < kR; ++r) {
          const float4 be4 = *(const float4*)(Bee + ((size_t)(e * kR + r)) * kH + c0 + tx * 4);
          lo[0] += lr[r] * be4.x; lo[1] += lr[r] * be4.y;
          lo[2] += lr[r] * be4.z; lo[3] += lr[r] * be4.w;
        }
        const float bb[4] = {bi4.x, bi4.y, bi4.z, bi4.w};
#pragma unroll
        for (int n = 0; n < 4; ++n)
          o[n] += wv[e] * (acc[e][m][n] + bb[n] + kLoraScale * lo[n]);
      }
    }
    *(float4*)(out + (size_t)t * kH + c0 + tx * 4) = make_float4(o[0], o[1], o[2], o[3]);
  }
}

// ---- cache copies + row-0 fixes + lb_loss ----
__global__ __launch_bounds__(256) void copyfix_k(
    const float* __restrict__ ck, const float* __restrict__ cv,
    const float* __restrict__ ci, const float* __restrict__ xsum,
    const float* __restrict__ newv0, const float* __restrict__ shadow,
    float* __restrict__ out) {
  const size_t NK = (size_t)kE * kC * kH;  // 4194304
  const size_t idx = (size_t)blockIdx.x * 256 + threadIdx.x;
  if (idx < NK) {
    const size_t c = (idx >> 10) & (kC - 1), h = idx & (kH - 1);
    out[OUT_NK + idx] = (c == 0) ? xsum[h] * (1.0f / kNT) : ck[idx];
  } else if (idx < 2 * NK) {
    const size_t j = idx - NK;
    const size_t e = j >> 20, c = (j >> 10) & (kC - 1), h = j & (kH - 1);
    out[OUT_NK + idx] = (c == 0) ? newv0[e * kH + h] : cv[j];
  } else if (idx < 2 * NK + (size_t)kE * kC) {
    const size_t j = idx - 2 * NK;
    out[OUT_NK + idx] = ((j & (kC - 1)) == 0) ? 1.0f : ci[j];
  } else if (idx == 2 * NK + (size_t)kE * kC) {
    float lb = 0.f;
#pragma unroll
    for (int e = 0; e < kE; ++e) {
      float ps = 0.f, cn = 0.f;
      for (int s2 = 0; s2 < 64; ++s2) {
        ps += shadow[s2 * 8 + e];
        cn += shadow[s2 * 8 + 4 + e];
      }
      lb += (ps * (1.0f / kNT)) * (cn * (1.0f / (kNT * 2.0f)));
    }
    out[OUT_LB] = kE * lb;
  }
}

extern "C" void kernel_launch(void* const* d_in, const int* in_sizes, int n_in,
                              void* d_out, int out_size, void* d_ws, size_t ws_size,
                              hipStream_t stream) {
  const float* x   = (const float*)d_in[0];
  const float* Wg  = (const float*)d_in[2];
  const float* bg  = (const float*)d_in[3];
  const float* We  = (const float*)d_in[12];
  const float* be  = (const float*)d_in[13];
  const float* Ae  = (const float*)d_in[14];
  const float* Bee = (const float*)d_in[15];
  const float* Av  = (const float*)d_in[16];
  const float* Bv  = (const float*)d_in[17];
  const float* ck  = (const float*)d_in[18];
  const float* cv  = (const float*)d_in[19];
  const float* ci  = (const float*)d_in[20];
  float* ws  = (float*)d_ws;
  float* out = (float*)d_out;

  hipMemsetAsync(ws + WS_XSUM, 0, (kH + 512) * sizeof(float), stream);
  router_k<<<kNT / 4, 256, 0, stream>>>(x, Wg, bg, Ae,
                                        ws + WS_RW, ws + WS_L, ws + WS_SHADOW);
  colsum_k<<<256, 256, 0, stream>>>(x, ws + WS_XSUM);
  expert_k<<<kE, 256, 0, stream>>>(ci, cv, Av, Bv, be, We, Ae, Bee,
                                   ws + WS_XSUM, ws + WS_BIAS, ws + WS_NEWV0);
  moe_gemm_k<<<dim3(kNT / 64, kH / 64), 256, 0, stream>>>(
      x, We, Bee, ws + WS_RW, ws + WS_L, ws + WS_BIAS, out);
  copyfix_k<<<32785, 256, 0, stream>>>(ck, cv, ci, ws + WS_XSUM, ws + WS_NEWV0,
                                       ws + WS_SHADOW, out);
}

// Round 2
// 516.268 us; speedup vs baseline: 3.9801x; 3.9801x over previous
//
#include <hip/hip_runtime.h>

constexpr int kH    = 1024;
constexpr int kNT   = 16384;   // B*S tokens
constexpr int kE    = 4;
constexpr int kC    = 1024;
constexpr int kR    = 4;
constexpr int kKeep = 512;
constexpr float kLoraScale = 0.25f;  // ALPHA / R

// ws layout (float offsets)
constexpr size_t WS_RW     = 0;         // kNT*kE            = 65536
constexpr size_t WS_L      = 65536;     // kNT*kE*kR         = 262144
constexpr size_t WS_XSUM   = 327680;    // kH
constexpr size_t WS_SHADOW = 328704;    // 64*8
constexpr size_t WS_TU     = 329216;    // kE*8
constexpr size_t WS_BIAS   = 329248;    // kE*kH
constexpr size_t WS_NEWV0  = 333344;    // kE*kH
constexpr size_t WS_VBAR   = 337440;    // kE*kH
constexpr size_t WS_KEEP   = 341536;    // kE*kC bytes (uchar)
constexpr size_t WS_XBF    = 342560;    // kNT*kH ushort = 8388608 floats
constexpr size_t WS_WET    = 8731168;   // kE*kH*kH ushort = 2097152 floats
constexpr size_t WS_AEXT   = 10828320;  // kNT*32 ushort = 262144 floats
constexpr size_t WS_BEXT   = 11090464;  // kH*32 ushort = 16384 floats
// total ~11.1M floats (~44.5 MB)

// out layout (float offsets)
constexpr size_t OUT_LB = 16777216;
constexpr size_t OUT_NK = 16777217;

typedef __attribute__((ext_vector_type(8))) short bf16x8;
typedef __attribute__((ext_vector_type(4))) float f32x4;

__device__ __forceinline__ float wred(float v) {
#pragma unroll
  for (int off = 32; off; off >>= 1) v += __shfl_xor(v, off);
  return v;
}

__device__ __forceinline__ ushort f2bf(float f) {  // RNE f32 -> bf16
  unsigned int u = __float_as_uint(f);
  u += 0x7FFFu + ((u >> 16) & 1u);
  return (ushort)(u >> 16);
}

__device__ __forceinline__ void gload16(const ushort* g, ushort* l) {
  __builtin_amdgcn_global_load_lds(
      (const __attribute__((address_space(1))) unsigned int*)g,
      (__attribute__((address_space(3))) unsigned int*)l, 16, 0, 0);
}

// ---- router: logits, softmax, top-2, routing weights, x@Ae, lb stats ----
__global__ __launch_bounds__(256) void router_k(
    const float* __restrict__ x, const float* __restrict__ Wg,
    const float* __restrict__ bg, const float* __restrict__ Ae,
    float* __restrict__ rw, float* __restrict__ Lw, float* __restrict__ shadow) {
  __shared__ float sblk[4][8];
  const int wave = threadIdx.x >> 6, lane = threadIdx.x & 63;
  const int t = blockIdx.x * 4 + wave;
  const float* xt = x + (size_t)t * kH;
  float p[kE] = {};
  float la[kE][kR] = {};
  for (int i = lane; i < kH; i += 64) {
    const float xv = xt[i];
    const float4 wg = *(const float4*)(Wg + (size_t)i * kE);
    p[0] += xv * wg.x; p[1] += xv * wg.y; p[2] += xv * wg.z; p[3] += xv * wg.w;
#pragma unroll
    for (int e = 0; e < kE; ++e) {
      const float4 ae = *(const float4*)(Ae + ((size_t)e * kH + i) * kR);
      la[e][0] += xv * ae.x; la[e][1] += xv * ae.y;
      la[e][2] += xv * ae.z; la[e][3] += xv * ae.w;
    }
  }
#pragma unroll
  for (int e = 0; e < kE; ++e) {
    p[e] = wred(p[e]);
#pragma unroll
    for (int r = 0; r < kR; ++r) la[e][r] = wred(la[e][r]);
  }
  if (lane == 0) {
    float lg[kE];
#pragma unroll
    for (int e = 0; e < kE; ++e) lg[e] = p[e] + bg[e];
    const float mx = fmaxf(fmaxf(lg[0], lg[1]), fmaxf(lg[2], lg[3]));
    float ex[kE], se = 0.f;
#pragma unroll
    for (int e = 0; e < kE; ++e) { ex[e] = __expf(lg[e] - mx); se += ex[e]; }
    float pr[kE];
#pragma unroll
    for (int e = 0; e < kE; ++e) pr[e] = ex[e] / se;
    int e1 = 0;
#pragma unroll
    for (int e = 1; e < kE; ++e) if (pr[e] > pr[e1]) e1 = e;
    int e2 = (e1 == 0) ? 1 : 0;
#pragma unroll
    for (int e = 0; e < kE; ++e) if (e != e1 && pr[e] > pr[e2]) e2 = e;
    const float s2 = pr[e1] + pr[e2];
    float rwv[kE] = {0.f, 0.f, 0.f, 0.f};
    rwv[e1] = pr[e1] / s2; rwv[e2] = pr[e2] / s2;
    *(float4*)(rw + (size_t)t * kE) = make_float4(rwv[0], rwv[1], rwv[2], rwv[3]);
#pragma unroll
    for (int e = 0; e < kE; ++e)
      *(float4*)(Lw + ((size_t)t * kE + e) * kR) =
          make_float4(la[e][0], la[e][1], la[e][2], la[e][3]);
#pragma unroll
    for (int e = 0; e < kE; ++e) {
      sblk[wave][e] = pr[e];
      sblk[wave][4 + e] = ((e == e1) ? 1.f : 0.f) + ((e == e2) ? 1.f : 0.f);
    }
  }
  __syncthreads();
  if (threadIdx.x < 8) {
    const float v = sblk[0][threadIdx.x] + sblk[1][threadIdx.x] +
                    sblk[2][threadIdx.x] + sblk[3][threadIdx.x];
    atomicAdd(&shadow[(blockIdx.x & 63) * 8 + threadIdx.x], v);
  }
}

// ---- fused: x f32 -> bf16 copy + column sums ----
__global__ __launch_bounds__(256) void xcvt_colsum_k(
    const float* __restrict__ x, ushort* __restrict__ xbf,
    float* __restrict__ xsum) {
  const int rg = blockIdx.x, tid = threadIdx.x;
  float s0 = 0.f, s1 = 0.f, s2 = 0.f, s3 = 0.f;
  const float* xp = x + (size_t)rg * 256 * kH + tid * 4;
  ushort* op = xbf + (size_t)rg * 256 * kH + tid * 4;
  for (int r = 0; r < 256; ++r) {
    const float4 v = *(const float4*)(xp + (size_t)r * kH);
    s0 += v.x; s1 += v.y; s2 += v.z; s3 += v.w;
    ushort4 u; u.x = f2bf(v.x); u.y = f2bf(v.y); u.z = f2bf(v.z); u.w = f2bf(v.w);
    *(ushort4*)(op + (size_t)r * kH) = u;
  }
  atomicAdd(&xsum[tid * 4 + 0], s0);
  atomicAdd(&xsum[tid * 4 + 1], s1);
  atomicAdd(&xsum[tid * 4 + 2], s2);
  atomicAdd(&xsum[tid * 4 + 3], s3);
}

// ---- transpose+convert We[e][k][j] -> WeT[e][j][k] bf16 ----
__global__ __launch_bounds__(256) void wet_k(const float* __restrict__ We,
                                             ushort* __restrict__ wet) {
  __shared__ ushort tile[64][72];
  const int jb = blockIdx.x, kb = blockIdx.y, e = blockIdx.z;
  const int tid = threadIdx.x;
  const int rr = tid >> 4, cq = tid & 15;
#pragma unroll
  for (int p = 0; p < 4; ++p) {
    const int k = kb * 64 + p * 16 + rr;
    const float4 v = *(const float4*)&We[((size_t)e * kH + k) * kH + jb * 64 + cq * 4];
    tile[p * 16 + rr][cq * 4 + 0] = f2bf(v.x);
    tile[p * 16 + rr][cq * 4 + 1] = f2bf(v.y);
    tile[p * 16 + rr][cq * 4 + 2] = f2bf(v.z);
    tile[p * 16 + rr][cq * 4 + 3] = f2bf(v.w);
  }
  __syncthreads();
#pragma unroll
  for (int p = 0; p < 4; ++p) {
    const int j = jb * 64 + p * 16 + rr;
    ushort4 u;
    u.x = tile[cq * 4 + 0][p * 16 + rr];
    u.y = tile[cq * 4 + 1][p * 16 + rr];
    u.z = tile[cq * 4 + 2][p * 16 + rr];
    u.w = tile[cq * 4 + 3][p * 16 + rr];
    *(ushort4*)&wet[((size_t)e * kH + j) * kH + kb * 64 + cq * 4] = u;
  }
}

// ---- keep mask (stable top-512 by importance) ----
__global__ __launch_bounds__(256) void keep_k(const float* __restrict__ ci,
                                              unsigned char* __restrict__ keep) {
  __shared__ float imp[kC];
  const int e = blockIdx.x, tid = threadIdx.x;
  for (int c = tid; c < kC; c += 256) imp[c] = ci[(size_t)e * kC + c];
  __syncthreads();
  for (int c = tid; c < kC; c += 256) {
    const float v = imp[c];
    int rank = 0;
    for (int c2 = 0; c2 < kC; ++c2) {
      const float v2 = imp[c2];
      rank += (v2 > v) || (v2 == v && c2 < c);
    }
    keep[(size_t)e * kC + c] = (rank < kKeep) ? 1 : 0;
  }
}

// ---- vbar (mean of kept cache rows) + t/u projections (atomic partials) ----
__global__ __launch_bounds__(256) void vbar_k(
    const unsigned char* __restrict__ keep, const float* __restrict__ cv,
    const float* __restrict__ Av, const float* __restrict__ Ae,
    const float* __restrict__ xsum, float* __restrict__ vbar,
    float* __restrict__ tu) {
  __shared__ unsigned char kp[kC];
  __shared__ float red[256];
  const int ch = blockIdx.x, e = blockIdx.y;
  const int tid = threadIdx.x;
  const int col = ch * 128 + (tid & 127), half = tid >> 7;
  for (int c = tid; c < kC; c += 256) kp[c] = keep[(size_t)e * kC + c];
  __syncthreads();
  float s = 0.f;
  const float* base = cv + (size_t)e * kC * kH + (size_t)half * 512 * kH + col;
  for (int r = 0; r < 512; ++r)
    if (kp[half * 512 + r]) s += base[(size_t)r * kH];
  red[tid] = s; __syncthreads();
  float pq[8];
  float vb = 0.f;
  if (tid < 128) {
    vb = (red[tid] + red[tid + 128]) * (1.0f / kKeep);
    vbar[(size_t)e * kH + col] = vb;
    const float xm = xsum[col] * (1.0f / kNT);
#pragma unroll
    for (int r = 0; r < kR; ++r) {
      pq[r] = vb * Av[((size_t)e * kH + col) * kR + r];
      pq[4 + r] = xm * Ae[((size_t)e * kH + col) * kR + r];
    }
  } else {
#pragma unroll
    for (int j = 0; j < 8; ++j) pq[j] = 0.f;
  }
  __syncthreads();
#pragma unroll
  for (int j = 0; j < 8; ++j) {
    red[tid] = pq[j]; __syncthreads();
    for (int s2 = 128; s2; s2 >>= 1) {
      if (tid < s2) red[tid] += red[tid + s2];
      __syncthreads();
    }
    if (tid == 0) atomicAdd(&tu[e * 8 + j], red[0]);
    __syncthreads();
  }
}

// ---- fx = xmean@We ; bias = be+vbar+0.25 t@Bv ; newv0 = fx+0.25 u@Be + bias ----
__global__ __launch_bounds__(256) void fxnv_k(
    const float* __restrict__ We, const float* __restrict__ Bv,
    const float* __restrict__ Bee, const float* __restrict__ be,
    const float* __restrict__ xsum, const float* __restrict__ vbar,
    const float* __restrict__ tu, float* __restrict__ bias_ws,
    float* __restrict__ newv0_ws) {
  __shared__ float xm[kH];
  __shared__ float red[256];
  const int ch = blockIdx.x, e = blockIdx.y;
  const int tid = threadIdx.x;
  const int col = ch * 128 + (tid & 127), half = tid >> 7;
  for (int k = tid; k < kH; k += 256) xm[k] = xsum[k] * (1.0f / kNT);
  __syncthreads();
  float s = 0.f;
  const float* Wb = We + (size_t)e * kH * kH + (size_t)half * 512 * kH + col;
  for (int k = 0; k < 512; ++k) s += xm[half * 512 + k] * Wb[(size_t)k * kH];
  red[tid] = s; __syncthreads();
  if (tid < 128) {
    const float fx = red[tid] + red[tid + 128];
    float lv = 0.f, le = 0.f;
#pragma unroll
    for (int r = 0; r < kR; ++r) {
      lv += tu[e * 8 + r] * Bv[((size_t)e * kR + r) * kH + col];
      le += tu[e * 8 + 4 + r] * Bee[((size_t)e * kR + r) * kH + col];
    }
    const float mv = vbar[(size_t)e * kH + col] + kLoraScale * lv;
    const float bias = be[(size_t)e * kH + col] + mv;
    bias_ws[(size_t)e * kH + col] = bias;
    newv0_ws[(size_t)e * kH + col] = fx + kLoraScale * le + bias;
  }
}

// ---- A-extension rows: [w_e (4) | 0.25*w_e*Lw (16) | zeros (12)] in bf16 ----
__global__ __launch_bounds__(256) void aext_k(const float* __restrict__ rw,
                                              const float* __restrict__ Lw,
                                              ushort* __restrict__ aext) {
  const int t = blockIdx.x * 256 + threadIdx.x;
  const float4 w4 = *(const float4*)&rw[(size_t)t * 4];
  const float w[4] = {w4.x, w4.y, w4.z, w4.w};
  __align__(16) ushort o[32];
#pragma unroll
  for (int e = 0; e < kE; ++e) o[e] = f2bf(w[e]);
#pragma unroll
  for (int e = 0; e < kE; ++e) {
    const float4 l4 = *(const float4*)&Lw[((size_t)t * kE + e) * kR];
    o[4 + e * 4 + 0] = f2bf(kLoraScale * w[e] * l4.x);
    o[4 + e * 4 + 1] = f2bf(kLoraScale * w[e] * l4.y);
    o[4 + e * 4 + 2] = f2bf(kLoraScale * w[e] * l4.z);
    o[4 + e * 4 + 3] = f2bf(kLoraScale * w[e] * l4.w);
  }
#pragma unroll
  for (int i = 20; i < 32; ++i) o[i] = 0;
#pragma unroll
  for (int q = 0; q < 4; ++q)
    *(float4*)&aext[(size_t)t * 32 + q * 8] = *(float4*)&o[q * 8];
}

// ---- B-extension: rows [bias_e (4) | Be (16) | zeros] as [j][32] bf16 ----
__global__ __launch_bounds__(256) void bext_k(const float* __restrict__ bias_ws,
                                              const float* __restrict__ Bee,
                                              ushort* __restrict__ bext) {
  const int j = blockIdx.x * 256 + threadIdx.x;
  __align__(16) ushort o[32];
#pragma unroll
  for (int e = 0; e < kE; ++e) o[e] = f2bf(bias_ws[(size_t)e * kH + j]);
#pragma unroll
  for (int e = 0; e < kE; ++e)
#pragma unroll
    for (int r = 0; r < kR; ++r)
      o[4 + e * 4 + r] = f2bf(Bee[((size_t)e * kR + r) * kH + j]);
#pragma unroll
  for (int i = 20; i < 32; ++i) o[i] = 0;
#pragma unroll
  for (int q = 0; q < 4; ++q)
    *(float4*)&bext[(size_t)j * 32 + q * 8] = *(float4*)&o[q * 8];
}

// ---- main MFMA GEMM: out[t][j] = sum over 33 K-segments (4 experts + ext) ----
__global__ __launch_bounds__(256, 2) void moe_gemm_k(
    const ushort* __restrict__ xbf, const ushort* __restrict__ wet,
    const ushort* __restrict__ aext, const ushort* __restrict__ bext,
    const float* __restrict__ rw, float* __restrict__ out) {
  __shared__ __align__(16) ushort As[2][128 * 32];
  __shared__ __align__(16) ushort Bs[2][128 * 32];
  __shared__ float w_s[128][4];
  const int tid = threadIdx.x;
  const int lane = tid & 63, wave = tid >> 6;
  const int wm = wave >> 1, wn = wave & 1;
  const int t0 = blockIdx.x * 128, c0 = blockIdx.y * 128;
  if (tid < 128) *(float4*)&w_s[tid][0] = *(const float4*)&rw[(size_t)(t0 + tid) * 4];

  const int srow = lane >> 2;       // row-within-16-chunk
  const int sslot = lane & 3;       // 16B slot within 64B row

  auto stage = [&](int buf, int kt) {
#pragma unroll
    for (int i = 0; i < 2; ++i) {
      const int j0 = wave * 32 + i * 16;
      const int r = j0 + srow;
      const int slot = sslot ^ ((r >> 1) & 3);
      const ushort* srcA;
      const ushort* srcB;
      if (kt < 128) {
        const int e = kt >> 5, k0 = (kt & 31) * 32;
        srcA = xbf + (size_t)(t0 + r) * kH + k0 + slot * 8;
        srcB = wet + ((size_t)(e * kH + c0 + r)) * kH + k0 + slot * 8;
      } else {
        srcA = aext + (size_t)(t0 + r) * 32 + slot * 8;
        srcB = bext + (size_t)(c0 + r) * 32 + slot * 8;
      }
      gload16(srcA, &As[buf][j0 * 32]);
      gload16(srcB, &Bs[buf][j0 * 32]);
    }
  };

  f32x4 accT[4][4] = {};
  f32x4 accE[4][4] = {};
  stage(0, 0);
  asm volatile("s_waitcnt vmcnt(0)" ::: "memory");
  __syncthreads();

  const int rA = lane & 15;
  const int fslot = lane >> 4;
  int buf = 0;
  for (int kt = 0; kt <= 128; ++kt) {
    if (kt < 128) stage(buf ^ 1, kt + 1);
    bf16x8 a[4], b[4];
#pragma unroll
    for (int m = 0; m < 4; ++m) {
      const int r = wm * 64 + m * 16 + rA;
      const int sl = fslot ^ ((r >> 1) & 3);
      a[m] = *(const bf16x8*)&As[buf][r * 32 + sl * 8];
    }
#pragma unroll
    for (int n = 0; n < 4; ++n) {
      const int r = wn * 64 + n * 16 + rA;
      const int sl = fslot ^ ((r >> 1) & 3);
      b[n] = *(const bf16x8*)&Bs[buf][r * 32 + sl * 8];
    }
#pragma unroll
    for (int m = 0; m < 4; ++m)
#pragma unroll
      for (int n = 0; n < 4; ++n)
        accE[m][n] = __builtin_amdgcn_mfma_f32_16x16x32_bf16(a[m], b[n], accE[m][n], 0, 0, 0);
    if ((kt & 31) == 31 || kt == 128) {
      const int e = kt >> 5;  // 0..3, or 4 => ext (weight 1)
#pragma unroll
      for (int m = 0; m < 4; ++m) {
        const int rbase = wm * 64 + m * 16 + (lane >> 4) * 4;
#pragma unroll
        for (int v = 0; v < 4; ++v) {
          const float w = (kt == 128) ? 1.0f : w_s[rbase + v][e];
#pragma unroll
          for (int n = 0; n < 4; ++n) {
            accT[m][n][v] += w * accE[m][n][v];
            accE[m][n][v] = 0.0f;
          }
        }
      }
    }
    if (kt < 128) asm volatile("s_waitcnt vmcnt(0)" ::: "memory");
    __syncthreads();
    buf ^= 1;
  }

#pragma unroll
  for (int m = 0; m < 4; ++m) {
    const int rbase = t0 + wm * 64 + m * 16 + (lane >> 4) * 4;
#pragma unroll
    for (int v = 0; v < 4; ++v) {
      float* orow = out + (size_t)(rbase + v) * kH + c0 + wn * 64 + (lane & 15);
#pragma unroll
      for (int n = 0; n < 4; ++n) orow[n * 16] = accT[m][n][v];
    }
  }
}

// ---- cache copies + row-0 fixes + lb_loss ----
__global__ __launch_bounds__(256) void copyfix_k(
    const float* __restrict__ ck, const float* __restrict__ cv,
    const float* __restrict__ ci, const float* __restrict__ xsum,
    const float* __restrict__ newv0, const float* __restrict__ shadow,
    float* __restrict__ out) {
  const size_t NK = (size_t)kE * kC * kH;  // 4194304
  const size_t idx = (size_t)blockIdx.x * 256 + threadIdx.x;
  if (idx < NK) {
    const size_t c = (idx >> 10) & (kC - 1), h = idx & (kH - 1);
    out[OUT_NK + idx] = (c == 0) ? xsum[h] * (1.0f / kNT) : ck[idx];
  } else if (idx < 2 * NK) {
    const size_t j = idx - NK;
    const size_t e = j >> 20, c = (j >> 10) & (kC - 1), h = j & (kH - 1);
    out[OUT_NK + idx] = (c == 0) ? newv0[e * kH + h] : cv[j];
  } else if (idx < 2 * NK + (size_t)kE * kC) {
    const size_t j = idx - 2 * NK;
    out[OUT_NK + idx] = ((j & (kC - 1)) == 0) ? 1.0f : ci[j];
  } else if (idx == 2 * NK + (size_t)kE * kC) {
    float lb = 0.f;
#pragma unroll
    for (int e = 0; e < kE; ++e) {
      float ps = 0.f, cn = 0.f;
      for (int s2 = 0; s2 < 64; ++s2) {
        ps += shadow[s2 * 8 + e];
        cn += shadow[s2 * 8 + 4 + e];
      }
      lb += (ps * (1.0f / kNT)) * (cn * (1.0f / (kNT * 2.0f)));
    }
    out[OUT_LB] = kE * lb;
  }
}

extern "C" void kernel_launch(void* const* d_in, const int* in_sizes, int n_in,
                              void* d_out, int out_size, void* d_ws, size_t ws_size,
                              hipStream_t stream) {
  const float* x   = (const float*)d_in[0];
  const float* Wg  = (const float*)d_in[2];
  const float* bg  = (const float*)d_in[3];
  const float* We  = (const float*)d_in[12];
  const float* be  = (const float*)d_in[13];
  const float* Ae  = (const float*)d_in[14];
  const float* Bee = (const float*)d_in[15];
  const float* Av  = (const float*)d_in[16];
  const float* Bv  = (const float*)d_in[17];
  const float* ck  = (const float*)d_in[18];
  const float* cv  = (const float*)d_in[19];
  const float* ci  = (const float*)d_in[20];
  float* ws  = (float*)d_ws;
  float* out = (float*)d_out;

  ushort* xbf  = (ushort*)(ws + WS_XBF);
  ushort* wet  = (ushort*)(ws + WS_WET);
  ushort* aext = (ushort*)(ws + WS_AEXT);
  ushort* bext = (ushort*)(ws + WS_BEXT);
  unsigned char* keep = (unsigned char*)(ws + WS_KEEP);

  // zero xsum + shadow + tu
  hipMemsetAsync(ws + WS_XSUM, 0, (1024 + 512 + 32) * sizeof(float), stream);
  xcvt_colsum_k<<<64, 256, 0, stream>>>(x, xbf, ws + WS_XSUM);
  router_k<<<kNT / 4, 256, 0, stream>>>(x, Wg, bg, Ae,
                                        ws + WS_RW, ws + WS_L, ws + WS_SHADOW);
  wet_k<<<dim3(16, 16, 4), 256, 0, stream>>>(We, wet);
  keep_k<<<kE, 256, 0, stream>>>(ci, keep);
  vbar_k<<<dim3(8, kE), 256, 0, stream>>>(keep, cv, Av, Ae, ws + WS_XSUM,
                                          ws + WS_VBAR, ws + WS_TU);
  fxnv_k<<<dim3(8, kE), 256, 0, stream>>>(We, Bv, Bee, be, ws + WS_XSUM,
                                          ws + WS_VBAR, ws + WS_TU,
                                          ws + WS_BIAS, ws + WS_NEWV0);
  aext_k<<<kNT / 256, 256, 0, stream>>>(ws + WS_RW, ws + WS_L, aext);
  bext_k<<<kH / 256, 256, 0, stream>>>(ws + WS_BIAS, Bee, bext);
  moe_gemm_k<<<dim3(kNT / 128, kH / 128), 256, 0, stream>>>(
      xbf, wet, aext, bext, ws + WS_RW, out);
  copyfix_k<<<32785, 256, 0, stream>>>(ck, cv, ci, ws + WS_XSUM, ws + WS_NEWV0,
                                       ws + WS_SHADOW, out);
}